// Round 5
// baseline (714.006 us; speedup 1.0000x reference)
//
#include <hip/hip_runtime.h>
#include <stdint.h>

// ---------------------------------------------------------------------------
// Fused 4-layer mini-BERT (B=32768, SEQ=4, D=128, H=4, DH=64) for gfx950.
// Round 5: barrier-free wave-autonomous design. Each wave owns 16 rows
// (4 batches); activations in wave-private LDS (46 KB/WG -> 3 WG/CU).
// Weights are read per-wave directly from the fragment-linear packed copy in
// d_ws (global, L2-resident) into a 64-VGPR register set, single-buffered;
// the stage epilogue VALU hides the L2 latency of next-stage loads.
// Zero __syncthreads in the entire kernel.
// ---------------------------------------------------------------------------

typedef __attribute__((ext_vector_type(8))) short    bf16x8;  // 8 bf16
typedef __attribute__((ext_vector_type(4))) _Float16 f16x4;
typedef __attribute__((ext_vector_type(4))) float    f32x4;

#define MFMA_BF(a,b,c) __builtin_amdgcn_mfma_f32_16x16x32_bf16((a),(b),(c),0,0,0)
#define MFMA_H(a,b,c)  __builtin_amdgcn_mfma_f32_16x16x16f16((a),(b),(c),0,0,0)

__device__ __forceinline__ unsigned short f2bf(float f){
  unsigned u = __float_as_uint(f);
  u += 0x7FFFu + ((u>>16)&1u);          // RNE
  return (unsigned short)(u>>16);
}
__device__ __forceinline__ unsigned pk2bf(float a, float b){
  return (unsigned)f2bf(a) | ((unsigned)f2bf(b)<<16);
}
__device__ __forceinline__ unsigned pkh(float a, float b){
  auto h = __builtin_amdgcn_cvt_pkrtz(a, b);    // v_cvt_pkrtz_f16_f32
  return __builtin_bit_cast(unsigned, h);
}
__device__ __forceinline__ void ubf2(unsigned u, float& a, float& b){
  a = __uint_as_float(u<<16);
  b = __uint_as_float(u & 0xffff0000u);
}

// ---------------- ws layout: 72 tiles of 8192 bf16 (16 KB), stage order -----
// tile t = l*18 + r;  r = h*4 + {0:wq,1:wk,2:wv,3:wo}, r=16:w1, r=17:w2.
// Each tile: 16 chunks of 512 elems; chunk c, lane, j ->
//   qkv/w1 (A/B-frag, m/n = f): f=(c>>2)*16+lnid, k=d=(c&3)*32+qid*8+j
//   wo/w2  (A-frag,   m = d) : d=(c>>1)*16+lnid, k=(c&1)*32+qid*8+j
// Fragment-linear: byte addr = t*16384 + c*1024 + lane*16 (coalesced b128).
__global__ __launch_bounds__(256) void prep_kernel(
    const float* __restrict__ wq, const float* __restrict__ wk,
    const float* __restrict__ wv, const float* __restrict__ wo,
    const float* __restrict__ w1, const float* __restrict__ w2,
    unsigned short* __restrict__ ws){
  int e16 = blockIdx.x*256 + threadIdx.x;       // 0..73727 (one uint4 each)
  int t    = e16 >> 10;
  int c    = (e16 >> 6) & 15;
  int lane = e16 & 63;
  int lnid = lane & 15, qid = lane >> 4;
  int l = t/18, r = t - l*18;
  float v[8];
  if (r < 16){
    int h = r >> 2, ty = r & 3;
    if (ty < 3){
      const float* W = (ty==0? wq : (ty==1? wk : wv)) + (size_t)(l*4+h)*8192;
      int f = (c>>2)*16 + lnid, d0 = (c&3)*32 + qid*8;
      #pragma unroll
      for (int j=0;j<8;++j) v[j] = W[(d0+j)*64 + f];
    } else {
      const float* W = wo + (size_t)l*32768 + (size_t)h*8192;  // rows h*64..
      int dd = (c>>1)*16 + lnid, k0 = (c&1)*32 + qid*8;
      #pragma unroll
      for (int j=0;j<8;++j) v[j] = W[(k0+j)*128 + dd];
    }
  } else if (r == 16){
    const float* W = w1 + (size_t)l*8192;
    int f = (c>>2)*16 + lnid, d0 = (c&3)*32 + qid*8;
    #pragma unroll
    for (int j=0;j<8;++j) v[j] = W[(d0+j)*64 + f];
  } else {
    const float* W = w2 + (size_t)l*8192;
    int dd = (c>>1)*16 + lnid, k0 = (c&1)*32 + qid*8;
    #pragma unroll
    for (int j=0;j<8;++j) v[j] = W[(k0+j)*128 + dd];
  }
  uint4 o;
  o.x = pk2bf(v[0],v[1]); o.y = pk2bf(v[2],v[3]);
  o.z = pk2bf(v[4],v[5]); o.w = pk2bf(v[6],v[7]);
  ((uint4*)ws)[e16] = o;
}

// ---------------- LDS layout (per wave / group of 16 rows, stride PG) -------
//  XOFF: X residual  bf16 [16][pitch 136]           4352 B
//  QOFF: Q [16][72] / ctx [16][72] / X2 [16][136] (spills into K region)
//  KOFF: K [16][72]
//  VOFF: V^T f16 [64][20] (2560 B) / h1 bf16 [16][72]
#define XOFF  0
#define QOFF  4352
#define KOFF  6656
#define VOFF  8960
#define PG    11520
#define LDSSZ 46080

__global__ __launch_bounds__(256,3) void bert_kernel(
    const float* __restrict__ emb,
    const float* __restrict__ bq, const float* __restrict__ bk, const float* __restrict__ bv,
    const float* __restrict__ bo,
    const float* __restrict__ ln1g, const float* __restrict__ ln1b,
    const float* __restrict__ fb1, const float* __restrict__ fb2,
    const float* __restrict__ ln2g, const float* __restrict__ ln2b,
    const unsigned short* __restrict__ ws,
    float* __restrict__ out)
{
  __shared__ __align__(16) char smem[LDSSZ];
  const int tid  = threadIdx.x;
  const int wid  = tid>>6;
  const int lane = tid&63;
  const int lnid = lane&15;
  const int qid  = lane>>4;
  const int batch0 = blockIdx.x*16;
  char* gb = smem + wid*PG;
  const f32x4 ZV = {0.f,0.f,0.f,0.f};

  // ---- initial X: embeddings[:, :4, :] -> bf16 LDS row-major [16][136] ----
  {
    int row = lane>>2, colq = (lane&3)*32;
    const float* src = emb + ((size_t)(batch0 + wid*4 + (row>>2))*6 + (row&3))*128 + colq;
    #pragma unroll
    for (int i=0;i<8;++i){
      float4 v = *(const float4*)(src + i*4);
      uint2 u; u.x = pk2bf(v.x,v.y); u.y = pk2bf(v.z,v.w);
      *(uint2*)(gb + XOFF + row*272 + (colq+i*4)*2) = u;
    }
  }
  // ---- passthrough: rows 4 (positive) and 5 (negatives) ----
  {
    const float* eb = emb + (size_t)batch0*768;
    float* o1 = out + 4194304 + (size_t)batch0*128;
    float* o2 = out + 8388608 + (size_t)batch0*128;
    #pragma unroll
    for (int i=0;i<4;++i){
      int idx = i*256 + tid;           // 0..1023 float4s
      int b = idx>>6, rem = idx&63;
      float4 v = *(const float4*)(eb + b*768 + 512 + rem*4);
      if (rem<32) *(float4*)(o1 + b*128 + rem*4) = v;
      else        *(float4*)(o2 + b*128 + (rem-32)*4) = v;
    }
  }

  // ---- weight registers: stage 0 tile, fragment-linear from global ----
  const char* wb = (const char*)ws;       // running tile base (uniform)
  const int lo16 = lane*16;
  bf16x8 w[16];
  #pragma unroll
  for (int c=0;c<16;++c) w[c] = *(const bf16x8*)(wb + c*1024 + lo16);

  f32x4  pacc[8];
  bf16x8 xfrag[4];

  for (int l=0; l<4; ++l){
    #pragma unroll
    for (int kc=0;kc<4;++kc)
      xfrag[kc] = *(const bf16x8*)(gb + XOFF + lnid*272 + kc*64 + qid*16);
    #pragma unroll
    for (int nt=0;nt<8;++nt) pacc[nt] = ZV;

    #pragma unroll
    for (int ph=0; ph<18; ++ph){
      if (ph < 16){
        int h = ph>>2, t = ph&3;
        if (t < 2){
          // ---- Q^T / K^T = W^T · X^T : A = W-frag, B = X-frag ----
          char* dst = gb + (t? KOFF : QOFF);
          const float* bias_base = (t? bk : bq) + (l*4+h)*64;
          #pragma unroll
          for (int nt=0; nt<4; ++nt){
            f32x4 a = ZV;
            #pragma unroll
            for (int kc=0; kc<4; ++kc)
              a = MFMA_BF(w[nt*4+kc], xfrag[kc], a);
            f32x4 bs = *(const f32x4*)(bias_base + nt*16 + qid*4);
            uint2 u; u.x = pk2bf(a[0]+bs[0], a[1]+bs[1]);
                     u.y = pk2bf(a[2]+bs[2], a[3]+bs[3]);
            *(uint2*)(dst + lnid*144 + nt*32 + qid*8) = u;   // [s][f] row-major
          }
        } else if (t == 2){
          // ---- V = X · Wv (unflipped): C regs = 4 rows s at col f -> V^T ----
          const float* bias_base = bv + (l*4+h)*64;
          #pragma unroll
          for (int nt=0; nt<4; ++nt){
            f32x4 a = ZV;
            #pragma unroll
            for (int kc=0; kc<4; ++kc)
              a = MFMA_BF(xfrag[kc], w[nt*4+kc], a);
            float b = bias_base[nt*16 + lnid];
            uint2 u; u.x = pkh(a[0]+b, a[1]+b);
                     u.y = pkh(a[2]+b, a[3]+b);
            *(uint2*)(gb + VOFF + (nt*16+lnid)*40 + qid*8) = u;  // V^T[f][s]
          }
        } else {
          // ---- attention + proj partial (w = wo tile for head h) ----
          bf16x8 kf0 = *(const bf16x8*)(gb+KOFF + lnid*144 + qid*16);
          bf16x8 kf1 = *(const bf16x8*)(gb+KOFF + lnid*144 + 64 + qid*16);
          bf16x8 qf0 = *(const bf16x8*)(gb+QOFF + lnid*144 + qid*16);
          bf16x8 qf1 = *(const bf16x8*)(gb+QOFF + lnid*144 + 64 + qid*16);
          // S^T[t][s] = K·Q^T : lane (col s=lnid) holds t = qid*4+r
          f32x4 st = MFMA_BF(kf0, qf0, ZV);
          st = MFMA_BF(kf1, qf1, st);
          float s0=st[0]*0.5f, s1=st[1]*0.5f, s2=st[2]*0.5f, s3=st[3]*0.5f;
          float mx = fmaxf(fmaxf(s0,s1), fmaxf(s2,s3));
          float p0=__expf(s0-mx), p1=__expf(s1-mx), p2=__expf(s2-mx), p3=__expf(s3-mx);
          float inv = 1.f/(p0+p1+p2+p3);
          bool valid = (lnid>>2) == qid;          // block-diagonal (4-batch tile)
          p0 = valid? p0*inv:0.f; p1 = valid? p1*inv:0.f;
          p2 = valid? p2*inv:0.f; p3 = valid? p3*inv:0.f;
          union { unsigned u[2]; f16x4 h4; } pu;
          pu.u[0] = pkh(p0,p1);
          pu.u[1] = pkh(p2,p3);
          f16x4 pf = pu.h4;                        // B-frag of 16x16x16 f16
          #pragma unroll
          for (int ft=0; ft<4; ++ft){
            f16x4 vf = *(const f16x4*)(gb+VOFF + (ft*16+lnid)*40 + qid*8);
            f32x4 c = MFMA_H(vf, pf, ZV);          // ctx^T[f][s]
            uint2 u; u.x = pk2bf(c[0],c[1]); u.y = pk2bf(c[2],c[3]);
            *(uint2*)(gb+QOFF + lnid*144 + ft*32 + qid*8) = u;  // ctx[s][f] over Q
          }
          asm volatile("" ::: "memory");
          bf16x8 c0 = *(const bf16x8*)(gb+QOFF + lnid*144 + qid*16);
          bf16x8 c1 = *(const bf16x8*)(gb+QOFF + lnid*144 + 64 + qid*16);
          #pragma unroll
          for (int nt=0; nt<8; ++nt){
            f32x4 a = pacc[nt];
            a = MFMA_BF(w[nt*2+0], c0, a);
            a = MFMA_BF(w[nt*2+1], c1, a);
            pacc[nt] = a;                           // proj^T: (s=lnid, d regs)
          }
        }
      } else if (ph == 16){
        // ---- +bo +residual, LN1, FF1+GELU (w = w1 tile) ----
        float sm=0.f, sq=0.f;
        #pragma unroll
        for (int nt=0;nt<8;++nt){
          f32x4 b4 = *(const f32x4*)(bo + l*128 + nt*16 + qid*4);
          uint2 xr = *(const uint2*)(gb+XOFF + lnid*272 + nt*32 + qid*8);
          float x0,x1,x2,x3; ubf2(xr.x,x0,x1); ubf2(xr.y,x2,x3);
          f32x4 a = pacc[nt];
          a[0]+=b4[0]+x0; a[1]+=b4[1]+x1; a[2]+=b4[2]+x2; a[3]+=b4[3]+x3;
          sm += a[0]+a[1]+a[2]+a[3];
          sq += a[0]*a[0]+a[1]*a[1]+a[2]*a[2]+a[3]*a[3];
          pacc[nt] = a;
        }
        sm += __shfl_xor(sm,16); sq += __shfl_xor(sq,16);
        sm += __shfl_xor(sm,32); sq += __shfl_xor(sq,32);
        float mu = sm*(1.f/128.f);
        float rs = rsqrtf(sq*(1.f/128.f) - mu*mu + 1e-5f);
        #pragma unroll
        for (int nt=0;nt<8;++nt){
          f32x4 g4 = *(const f32x4*)(ln1g + l*128 + nt*16 + qid*4);
          f32x4 be = *(const f32x4*)(ln1b + l*128 + nt*16 + qid*4);
          f32x4 a = pacc[nt];
          float v0 = (a[0]-mu)*rs*g4[0]+be[0];
          float v1 = (a[1]-mu)*rs*g4[1]+be[1];
          float v2 = (a[2]-mu)*rs*g4[2]+be[2];
          float v3 = (a[3]-mu)*rs*g4[3]+be[3];
          uint2 u; u.x = pk2bf(v0,v1); u.y = pk2bf(v2,v3);
          *(uint2*)(gb+QOFF + lnid*272 + nt*32 + qid*8) = u;   // X2 [16][136]
        }
        asm volatile("" ::: "memory");
        bf16x8 x2f[4];
        #pragma unroll
        for (int kc=0;kc<4;++kc)
          x2f[kc] = *(const bf16x8*)(gb+QOFF + lnid*272 + kc*64 + qid*16);
        #pragma unroll
        for (int nt=0; nt<4; ++nt){
          f32x4 a = ZV;
          #pragma unroll
          for (int kc=0; kc<4; ++kc)
            a = MFMA_BF(w[nt*4+kc], x2f[kc], a);
          f32x4 b1 = *(const f32x4*)(fb1 + l*64 + nt*16 + qid*4);
          float g0,g1,g2,g3;
          { float x = a[0]+b1[0]; g0 = 0.5f*x*(1.f+erff(x*0.70710678f)); }
          { float x = a[1]+b1[1]; g1 = 0.5f*x*(1.f+erff(x*0.70710678f)); }
          { float x = a[2]+b1[2]; g2 = 0.5f*x*(1.f+erff(x*0.70710678f)); }
          { float x = a[3]+b1[3]; g3 = 0.5f*x*(1.f+erff(x*0.70710678f)); }
          uint2 u; u.x = pk2bf(g0,g1); u.y = pk2bf(g2,g3);
          *(uint2*)(gb+VOFF + lnid*144 + nt*32 + qid*8) = u;   // h1 [16][72]
        }
        asm volatile("" ::: "memory");
      } else {
        // ---- FF2 + residual + LN2 -> new X (w = w2 tile) ----
        bf16x8 h0  = *(const bf16x8*)(gb+VOFF + lnid*144 + qid*16);
        bf16x8 h1f = *(const bf16x8*)(gb+VOFF + lnid*144 + 64 + qid*16);
        f32x4 racc[8];
        #pragma unroll
        for (int nt=0; nt<8; ++nt){
          f32x4 a = MFMA_BF(w[nt*2+0], h0, ZV);
          a = MFMA_BF(w[nt*2+1], h1f, a);
          racc[nt] = a;
        }
        float sm=0.f, sq=0.f;
        #pragma unroll
        for (int nt=0;nt<8;++nt){
          f32x4 b4 = *(const f32x4*)(fb2 + l*128 + nt*16 + qid*4);
          uint2 xr = *(const uint2*)(gb+XOFF + lnid*272 + nt*32 + qid*8);
          float x0,x1,x2,x3; ubf2(xr.x,x0,x1); ubf2(xr.y,x2,x3);
          f32x4 a = racc[nt];
          a[0]+=b4[0]+x0; a[1]+=b4[1]+x1; a[2]+=b4[2]+x2; a[3]+=b4[3]+x3;
          sm += a[0]+a[1]+a[2]+a[3];
          sq += a[0]*a[0]+a[1]*a[1]+a[2]*a[2]+a[3]*a[3];
          racc[nt] = a;
        }
        sm += __shfl_xor(sm,16); sq += __shfl_xor(sq,16);
        sm += __shfl_xor(sm,32); sq += __shfl_xor(sq,32);
        float mu = sm*(1.f/128.f);
        float rs = rsqrtf(sq*(1.f/128.f) - mu*mu + 1e-5f);
        #pragma unroll
        for (int nt=0;nt<8;++nt){
          f32x4 g4 = *(const f32x4*)(ln2g + l*128 + nt*16 + qid*4);
          f32x4 be = *(const f32x4*)(ln2b + l*128 + nt*16 + qid*4);
          f32x4 a = racc[nt];
          float v0 = (a[0]-mu)*rs*g4[0]+be[0];
          float v1 = (a[1]-mu)*rs*g4[1]+be[1];
          float v2 = (a[2]-mu)*rs*g4[2]+be[2];
          float v3 = (a[3]-mu)*rs*g4[3]+be[3];
          uint2 u; u.x = pk2bf(v0,v1); u.y = pk2bf(v2,v3);
          *(uint2*)(gb+XOFF + lnid*272 + nt*32 + qid*8) = u;   // new X
        }
        asm volatile("" ::: "memory");
      }

      // ---- advance to next weight tile; reload register set ----
      wb += 16384;
      if (l < 3 || ph < 17){
        #pragma unroll
        for (int c=0;c<16;++c) w[c] = *(const bf16x8*)(wb + c*1024 + lo16);
      }
    }
  }

  // ---- epilogue: final_embedding = mean over 4 seq rows ----
  {
    int bl = lane>>4;                 // batch within group
    float acc[8] = {0,0,0,0,0,0,0,0};
    #pragma unroll
    for (int s=0;s<4;++s){
      uint4 u = *(const uint4*)(gb + XOFF + (bl*4+s)*272 + lnid*16);
      float a0,a1;
      ubf2(u.x,a0,a1); acc[0]+=a0; acc[1]+=a1;
      ubf2(u.y,a0,a1); acc[2]+=a0; acc[3]+=a1;
      ubf2(u.z,a0,a1); acc[4]+=a0; acc[5]+=a1;
      ubf2(u.w,a0,a1); acc[6]+=a0; acc[7]+=a1;
    }
    float* dst = out + (size_t)(batch0 + wid*4 + bl)*128 + lnid*8;
    f32x4 v0 = {acc[0]*0.25f, acc[1]*0.25f, acc[2]*0.25f, acc[3]*0.25f};
    f32x4 v1 = {acc[4]*0.25f, acc[5]*0.25f, acc[6]*0.25f, acc[7]*0.25f};
    *(f32x4*)dst = v0;
    *(f32x4*)(dst+4) = v1;
  }
}

extern "C" void kernel_launch(void* const* d_in, const int* in_sizes, int n_in,
                              void* d_out, int out_size, void* d_ws, size_t ws_size,
                              hipStream_t stream) {
  const float* emb  = (const float*)d_in[0];
  const float* wq   = (const float*)d_in[1];
  const float* bq   = (const float*)d_in[2];
  const float* wk   = (const float*)d_in[3];
  const float* bk   = (const float*)d_in[4];
  const float* wv   = (const float*)d_in[5];
  const float* bv   = (const float*)d_in[6];
  const float* wo   = (const float*)d_in[7];
  const float* bo   = (const float*)d_in[8];
  const float* ln1g = (const float*)d_in[9];
  const float* ln1b = (const float*)d_in[10];
  const float* fw1  = (const float*)d_in[11];
  const float* fb1  = (const float*)d_in[12];
  const float* fw2  = (const float*)d_in[13];
  const float* fb2  = (const float*)d_in[14];
  const float* ln2g = (const float*)d_in[15];
  const float* ln2b = (const float*)d_in[16];
  unsigned short* ws = (unsigned short*)d_ws;
  float* out = (float*)d_out;

  prep_kernel<<<288, 256, 0, stream>>>(wq, wk, wv, wo, fw1, fw2, ws);
  bert_kernel<<<2048, 256, 0, stream>>>(emb, bq, bk, bv, bo, ln1g, ln1b,
                                        fb1, fb2, ln2g, ln2b, ws, out);
}